// Round 6
// baseline (268.441 us; speedup 1.0000x reference)
//
#include <hip/hip_runtime.h>
#include <hip/hip_bf16.h>
#include <math.h>

typedef __bf16 bf16;
typedef __bf16 bf16x4 __attribute__((ext_vector_type(4)));
typedef __bf16 bf16x8 __attribute__((ext_vector_type(8)));
typedef float  f32x4  __attribute__((ext_vector_type(4)));

#define B_  4
#define S_  2048
#define D_  1024
#define H_  16
#define DH  64
#define M_  (B_*S_)      // 8192
#define BH_ (B_*H_)      // 64

// 1/sqrt(64) * log2(e): folded into Q so attn uses exp2 directly
#define QSCALE 0.18033688011112042f

__device__ __forceinline__ void glds16(const bf16* g, bf16* l) {
  __builtin_amdgcn_global_load_lds((const __attribute__((address_space(1))) void*)g,
                                   (__attribute__((address_space(3))) void*)l, 16, 0, 0);
}

// -------------------- prep: weight transposes only (hidden cvt fused into gemm_qkv) ---------
__global__ __launch_bounds__(256) void prep(const float* __restrict__ wqkv, const float* __restrict__ wout,
                                            bf16* __restrict__ wqkvT, bf16* __restrict__ woutT) {
  __shared__ float tile[32][33];
  int t = blockIdx.x, tid = threadIdx.x;
  const float* in; bf16* out; int C, c0, r0;
  if (t < 96 * 32) { in = wqkv; out = wqkvT; C = 3072; c0 = (t % 96) * 32; r0 = (t / 96) * 32; }
  else { t -= 96 * 32;  in = wout; out = woutT; C = 1024; c0 = (t % 32) * 32; r0 = (t / 32) * 32; }
  int tx = tid & 31, ty = tid >> 5;
  #pragma unroll
  for (int i = ty; i < 32; i += 8) tile[i][tx] = in[(size_t)(r0 + i) * C + c0 + tx];
  __syncthreads();
  #pragma unroll
  for (int i = ty; i < 32; i += 8) out[(size_t)(c0 + i) * D_ + r0 + tx] = (bf16)tile[tx][i];
}

// ==================== R0 128x128 GEMM core (proven band), template<SW> =======================
// SW=0: acc[i][j] = mfma(af, bfr) -> acc reg r spans m.  SW=1: acc[j][i] = mfma(bfr, af) ->
// reg r spans n. Chosen per output consumer for vectorized stores (R5 harness-verified).
#define LDA2 32
#define SUB  (128 * LDA2)   // elements per k-half sub-tile

// Variant A: both operands bf16, staged via global_load_lds (EXACT R0 structure).
template<bool SW>
__device__ __forceinline__ void core128(const bf16* __restrict__ A, const bf16* __restrict__ Bt,
                                        int m0, int n0, bf16* As, bf16* Bs,
                                        int tid, f32x4 acc[4][4]) {
  int wave = tid >> 6, lane = tid & 63, quad = lane >> 4, l16 = lane & 15;
  int wm = (wave >> 1) * 64, wn = (wave & 1) * 64;
  int lr = lane >> 2, lc = (lane & 3) * 8;
  const bf16* gA = A  + (size_t)(m0 + wave * 32 + lr) * D_ + lc;
  const bf16* gB = Bt + (size_t)(n0 + wave * 32 + lr) * D_ + lc;
  bf16* lA = As + wave * 32 * LDA2;
  bf16* lB = Bs + wave * 32 * LDA2;
  for (int k0 = 0; k0 < D_; k0 += 64) {
    #pragma unroll
    for (int h = 0; h < 2; h++) {
      int kk = k0 + h * 32;
      glds16(gA + kk,           lA + h * SUB);
      glds16(gA + kk + 16 * D_, lA + h * SUB + 16 * LDA2);
      glds16(gB + kk,           lB + h * SUB);
      glds16(gB + kk + 16 * D_, lB + h * SUB + 16 * LDA2);
    }
    __syncthreads();
    #pragma unroll
    for (int h = 0; h < 2; h++) {
      bf16x8 af[4], bff[4];
      #pragma unroll
      for (int i = 0; i < 4; i++) af[i]  = *(const bf16x8*)(As + h * SUB + (wm + i * 16 + l16) * LDA2 + quad * 8);
      #pragma unroll
      for (int j = 0; j < 4; j++) bff[j] = *(const bf16x8*)(Bs + h * SUB + (wn + j * 16 + l16) * LDA2 + quad * 8);
      #pragma unroll
      for (int i = 0; i < 4; i++)
        #pragma unroll
        for (int j = 0; j < 4; j++) {
          if constexpr (SW)
            acc[j][i] = __builtin_amdgcn_mfma_f32_16x16x32_bf16(bff[j], af[i], acc[j][i], 0, 0, 0);
          else
            acc[i][j] = __builtin_amdgcn_mfma_f32_16x16x32_bf16(af[i], bff[j], acc[i][j], 0, 0, 0);
        }
    }
    __syncthreads();
  }
}

// Variant B: A read directly as fp32 (hidden), reg-staged + cvt + ds_write_b128 into the SAME
// LDS layout as glds16 would produce (lane l -> chunk offset l*16B); B via global_load_lds.
// Fuses prep's hidden conversion into the GEMM: kills 48 MB of prep traffic + the hb buffer.
template<bool SW>
__device__ __forceinline__ void coreA32(const float* __restrict__ Af, const bf16* __restrict__ Bt,
                                        int m0, int n0, bf16* As, bf16* Bs,
                                        int tid, f32x4 acc[4][4]) {
  int wave = tid >> 6, lane = tid & 63, quad = lane >> 4, l16 = lane & 15;
  int wm = (wave >> 1) * 64, wn = (wave & 1) * 64;
  int lr = lane >> 2, lc = (lane & 3) * 8;
  const float* gA = Af + (size_t)(m0 + wave * 32 + lr) * D_ + lc;
  const bf16*  gB = Bt + (size_t)(n0 + wave * 32 + lr) * D_ + lc;
  bf16* lB = Bs + wave * 32 * LDA2;
  bf16* wA = As + wave * 32 * LDA2 + lane * 8;   // lane's write slot in its wave's chunk
  for (int k0 = 0; k0 < D_; k0 += 64) {
    #pragma unroll
    for (int h = 0; h < 2; h++) {
      int kk = k0 + h * 32;
      glds16(gB + kk,           lB + h * SUB);
      glds16(gB + kk + 16 * D_, lB + h * SUB + 16 * LDA2);
    }
    #pragma unroll
    for (int h = 0; h < 2; h++) {
      int kk = k0 + h * 32;
      #pragma unroll
      for (int c = 0; c < 2; c++) {              // row chunks lr and lr+16
        const float* src = gA + kk + (size_t)(c * 16) * D_;
        float4 v0 = *(const float4*)(src);
        float4 v1 = *(const float4*)(src + 4);
        bf16x8 w = { (bf16)v0.x, (bf16)v0.y, (bf16)v0.z, (bf16)v0.w,
                     (bf16)v1.x, (bf16)v1.y, (bf16)v1.z, (bf16)v1.w };
        *(bf16x8*)(wA + h * SUB + c * 16 * LDA2) = w;
      }
    }
    __syncthreads();   // drains vmcnt (glds) AND lgkmcnt (ds_write) before any frag read
    #pragma unroll
    for (int h = 0; h < 2; h++) {
      bf16x8 af[4], bff[4];
      #pragma unroll
      for (int i = 0; i < 4; i++) af[i]  = *(const bf16x8*)(As + h * SUB + (wm + i * 16 + l16) * LDA2 + quad * 8);
      #pragma unroll
      for (int j = 0; j < 4; j++) bff[j] = *(const bf16x8*)(Bs + h * SUB + (wn + j * 16 + l16) * LDA2 + quad * 8);
      #pragma unroll
      for (int i = 0; i < 4; i++)
        #pragma unroll
        for (int j = 0; j < 4; j++) {
          if constexpr (SW)
            acc[j][i] = __builtin_amdgcn_mfma_f32_16x16x32_bf16(bff[j], af[i], acc[j][i], 0, 0, 0);
          else
            acc[i][j] = __builtin_amdgcn_mfma_f32_16x16x32_bf16(af[i], bff[j], acc[i][j], 0, 0, 0);
        }
    }
    __syncthreads();
  }
}

// GEMM1: qkv = hidden(fp32) @ w_qkv. Q gets QSCALE folded; V written transposed.
// XCD swizzle (T1): grid 24x64 = 1536 = 8 XCD x 192; each XCD owns 8 contiguous m-rows x all
// 24 n-panels -> A-panel fetched by exactly ONE XCD (concurrent A set ~3MB < 4MB L2).
__global__ __launch_bounds__(256) void gemm_qkv(const float* __restrict__ hidden, const bf16* __restrict__ Bt,
                                                bf16* __restrict__ Qb, bf16* __restrict__ Kb,
                                                bf16* __restrict__ Vtb) {
  __shared__ __attribute__((aligned(16))) bf16 As[2 * SUB];
  __shared__ __attribute__((aligned(16))) bf16 Bs[2 * SUB];
  int tid = threadIdx.x;
  int lin = blockIdx.y * 24 + blockIdx.x;
  int xcd = lin & 7, idx = lin >> 3;            // bijective: 1536 = 8*192, 192 = 8*24
  int m0 = ((xcd << 3) + (idx / 24)) * 128;
  int n0 = (idx % 24) * 128;
  int wave = tid >> 6, lane = tid & 63, quad = lane >> 4, l16 = lane & 15;
  int wm = (wave >> 1) * 64, wn = (wave & 1) * 64;
  int which = n0 >> 10;                         // 0=Q 1=K 2=V, block-uniform
  f32x4 acc[4][4] = {};
  if (which == 2) {
    coreA32<false>(hidden, Bt, m0, n0, As, Bs, tid, acc);
    #pragma unroll
    for (int i = 0; i < 4; i++) {
      int mb = m0 + wm + i * 16 + quad * 4;
      int b = mb >> 11, s = mb & 2047;
      #pragma unroll
      for (int j = 0; j < 4; j++) {
        int n = n0 + wn + j * 16 + l16;
        int h = (n >> 6) & 15, dd = n & 63;
        bf16x4 v4 = { (bf16)acc[i][j][0], (bf16)acc[i][j][1], (bf16)acc[i][j][2], (bf16)acc[i][j][3] };
        *(bf16x4*)(Vtb + ((size_t)(b * H_ + h) * DH + dd) * S_ + s) = v4;
      }
    }
  } else {
    coreA32<true>(hidden, Bt, m0, n0, As, Bs, tid, acc);
    bf16* dst = (which == 0) ? Qb : Kb;
    float sc = (which == 0) ? QSCALE : 1.0f;
    #pragma unroll
    for (int i = 0; i < 4; i++) {
      int m = m0 + wm + i * 16 + l16;           // col = l16 -> m (sequence position)
      int b = m >> 11, s = m & 2047;
      #pragma unroll
      for (int j = 0; j < 4; j++) {
        int n = n0 + wn + j * 16 + quad * 4;    // reg r spans dd; head constant over r
        int h = (n >> 6) & 15, dd = n & 63;
        bf16x4 v4 = { (bf16)(acc[j][i][0] * sc), (bf16)(acc[j][i][1] * sc),
                      (bf16)(acc[j][i][2] * sc), (bf16)(acc[j][i][3] * sc) };
        *(bf16x4*)(dst + (((size_t)(b * H_ + h)) * S_ + s) * DH + dd) = v4;
      }
    }
  }
}

// GEMM2: out = ctx @ w_out, fp32 output. Native mapping already co-locates A-sharing blocks
// per XCD (xcd = blockIdx.x % 8, A-panel = same blockIdx.x). SW=1 -> 16 coalesced float4 stores.
__global__ __launch_bounds__(256) void gemm_out(const bf16* __restrict__ A, const bf16* __restrict__ Bt,
                                                float* __restrict__ C) {
  __shared__ __attribute__((aligned(16))) bf16 As[2 * SUB];
  __shared__ __attribute__((aligned(16))) bf16 Bs[2 * SUB];
  int tid = threadIdx.x;
  int m0 = blockIdx.x * 128, n0 = blockIdx.y * 128;
  f32x4 acc[4][4] = {};
  core128<true>(A, Bt, m0, n0, As, Bs, tid, acc);
  int wave = tid >> 6, lane = tid & 63, quad = lane >> 4, l16 = lane & 15;
  int wm = (wave >> 1) * 64, wn = (wave & 1) * 64;
  #pragma unroll
  for (int i = 0; i < 4; i++) {
    int m = m0 + wm + i * 16 + l16;
    #pragma unroll
    for (int j = 0; j < 4; j++) {
      int n = n0 + wn + j * 16 + quad * 4;
      *(f32x4*)(&C[(size_t)m * D_ + n]) = acc[j][i];
    }
  }
}

// -------------------- flash attention (unchanged: control, 81.3-83us band) ------------------
#define NT  (S_ / 64)

#define KVSW(row, col) (((row) * 64) + ((col) ^ (((row) & 7) << 3)))
#define PSW(row, col)  (((row) * 32) + ((col) ^ ((((row) >> 1) & 3) << 3)))

__global__ __launch_bounds__(256, 2) void attn(const bf16* __restrict__ Qb, const bf16* __restrict__ Kb,
                                               const bf16* __restrict__ Vtb, bf16* __restrict__ ctx) {
  __shared__ __attribute__((aligned(16))) bf16 Ks[2][64 * 64];   // [buf][key][dd], swizzled
  __shared__ __attribute__((aligned(16))) bf16 Vs[2][64 * 64];   // [buf][dd][key], swizzled
  __shared__ __attribute__((aligned(16))) bf16 Ps[4][64 * 32];   // per-wave P half: [q(64)][key(32)], swizzled
  int tid = threadIdx.x;
  int wave = tid >> 6, lane = tid & 63, quad = lane >> 4, l16 = lane & 15;
  int bh = blockIdx.x;                  // x-major: XCD = bh % 8 -> K/V working set stays in one L2
  int b = bh >> 4, h = bh & 15;
  int q0 = blockIdx.y * 256 + wave * 64;
  const bf16* Qp = Qb  + (size_t)bh * S_ * DH;
  const bf16* Kp = Kb  + (size_t)bh * S_ * DH;
  const bf16* Vp = Vtb + (size_t)bh * DH * S_;

  int srow = tid >> 3, scc = (tid & 7) << 3;
  int swz = KVSW(srow, scc);            // staging slot for rows srow / srow+32 (same &7)

  bf16x8 qf[4][2];
  #pragma unroll
  for (int nq = 0; nq < 4; nq++)
    #pragma unroll
    for (int ks = 0; ks < 2; ks++)
      qf[nq][ks] = *(const bf16x8*)(Qp + (size_t)(q0 + nq * 16 + l16) * DH + ks * 32 + quad * 8);

  bf16 one1 = (bf16)1.0f;
  bf16x8 onesf = { one1, one1, one1, one1, one1, one1, one1, one1 };

  f32x4 o[4][4] = {};       // o[nq][td]: row q = quad*4+r, col dd = td*16+l16
  f32x4 oden[4] = {};       // denom(q), same row mapping

  {
    bf16x8 k0a = *(const bf16x8*)(Kp + (size_t)srow * DH + scc);
    bf16x8 k0b = *(const bf16x8*)(Kp + (size_t)(32 + srow) * DH + scc);
    bf16x8 v0a = *(const bf16x8*)(Vp + (size_t)srow * S_ + scc);
    bf16x8 v0b = *(const bf16x8*)(Vp + (size_t)(32 + srow) * S_ + scc);
    *(bf16x8*)(Ks[0] + swz)             = k0a;
    *(bf16x8*)(Ks[0] + swz + 32 * 64)   = k0b;
    *(bf16x8*)(Vs[0] + swz)             = v0a;
    *(bf16x8*)(Vs[0] + swz + 32 * 64)   = v0b;
  }

  for (int kt = 0; kt < NT; kt++) {
    int cur = kt & 1;
    __syncthreads();

    bf16x8 ka, kb2, va, vb;
    if (kt + 1 < NT) {
      const bf16* Kn = Kp + (size_t)(kt + 1) * 64 * DH;
      const bf16* Vn = Vp + (size_t)(kt + 1) * 64;
      ka  = *(const bf16x8*)(Kn + (size_t)srow * DH + scc);
      kb2 = *(const bf16x8*)(Kn + (size_t)(32 + srow) * DH + scc);
      va  = *(const bf16x8*)(Vn + (size_t)srow * S_ + scc);
      vb  = *(const bf16x8*)(Vn + (size_t)(32 + srow) * S_ + scc);
    }

    bf16x8 vf[4][2];
    #pragma unroll
    for (int td = 0; td < 4; td++)
      #pragma unroll
      for (int ks = 0; ks < 2; ks++)
        vf[td][ks] = *(const bf16x8*)(Vs[cur] + KVSW(td * 16 + l16, ks * 32 + quad * 8));

    #pragma unroll
    for (int hh = 0; hh < 2; hh++) {
      #pragma unroll
      for (int kq2 = 0; kq2 < 2; kq2++) {
        int kq = hh * 2 + kq2;
        bf16x8 kfr[2];
        #pragma unroll
        for (int ks = 0; ks < 2; ks++)
          kfr[ks] = *(const bf16x8*)(Ks[cur] + KVSW(kq * 16 + l16, ks * 32 + quad * 8));
        #pragma unroll
        for (int nq = 0; nq < 4; nq++) {
          f32x4 st = {};
          st = __builtin_amdgcn_mfma_f32_16x16x32_bf16(kfr[0], qf[nq][0], st, 0, 0, 0);
          st = __builtin_amdgcn_mfma_f32_16x16x32_bf16(kfr[1], qf[nq][1], st, 0, 0, 0);
          bf16x4 pk;
          #pragma unroll
          for (int r = 0; r < 4; r++) pk[r] = (bf16)__builtin_amdgcn_exp2f(st[r]);
          *(bf16x4*)(&Ps[wave][PSW(nq * 16 + l16, kq2 * 16 + quad * 4)]) = pk;
        }
      }
      #pragma unroll
      for (int nq = 0; nq < 4; nq++) {
        bf16x8 pf = *(const bf16x8*)(&Ps[wave][PSW(nq * 16 + l16, quad * 8)]);
        oden[nq] = __builtin_amdgcn_mfma_f32_16x16x32_bf16(pf, onesf, oden[nq], 0, 0, 0);
        #pragma unroll
        for (int td = 0; td < 4; td++)
          o[nq][td] = __builtin_amdgcn_mfma_f32_16x16x32_bf16(pf, vf[td][hh], o[nq][td], 0, 0, 0);
      }
    }

    if (kt + 1 < NT) {
      int nxt = cur ^ 1;
      *(bf16x8*)(Ks[nxt] + swz)           = ka;
      *(bf16x8*)(Ks[nxt] + swz + 32 * 64) = kb2;
      *(bf16x8*)(Vs[nxt] + swz)           = va;
      *(bf16x8*)(Vs[nxt] + swz + 32 * 64) = vb;
    }
  }

  #pragma unroll
  for (int nq = 0; nq < 4; nq++) {
    #pragma unroll
    for (int r = 0; r < 4; r++) {
      float inv = 1.0f / oden[nq][r];
      int q = q0 + nq * 16 + quad * 4 + r;
      #pragma unroll
      for (int td = 0; td < 4; td++) {
        int dd = td * 16 + l16;
        ctx[((size_t)(b * S_) + q) * D_ + h * DH + dd] = (bf16)(o[nq][td][r] * inv);
      }
    }
  }
}

// -------------------- host launch --------------------
extern "C" void kernel_launch(void* const* d_in, const int* in_sizes, int n_in,
                              void* d_out, int out_size, void* d_ws, size_t ws_size,
                              hipStream_t stream) {
  (void)in_sizes; (void)n_in; (void)out_size; (void)ws_size;
  const float* hidden = (const float*)d_in[0];
  const float* w_qkv  = (const float*)d_in[1];
  const float* w_out  = (const float*)d_in[2];
  float* out = (float*)d_out;

  char* ws = (char*)d_ws;
  size_t off = 0;
  bf16* ctxb  = (bf16*)(ws + off); off += (size_t)M_ * D_ * 2;      // attn output
  bf16* wqkvT = (bf16*)(ws + off); off += (size_t)3 * D_ * D_ * 2;  // [3072][1024]
  bf16* woutT = (bf16*)(ws + off); off += (size_t)D_ * D_ * 2;      // [1024][1024]
  bf16* Qb    = (bf16*)(ws + off); off += (size_t)M_ * D_ * 2;      // [BH][S][DH], pre-scaled
  bf16* Kb    = (bf16*)(ws + off); off += (size_t)M_ * D_ * 2;      // [BH][S][DH]
  bf16* Vtb   = (bf16*)(ws + off); off += (size_t)M_ * D_ * 2;      // [BH][DH][S]

  prep<<<96 * 32 + 32 * 32, 256, 0, stream>>>(w_qkv, w_out, wqkvT, woutT);
  gemm_qkv<<<dim3(24, 64), 256, 0, stream>>>(hidden, wqkvT, Qb, Kb, Vtb);
  attn<<<dim3(BH_, S_ / 256), 256, 0, stream>>>(Qb, Kb, Vtb, ctxb);
  gemm_out<<<dim3(M_ / 128, D_ / 128), 256, 0, stream>>>(ctxb, woutT, out);
}

// Round 7
// 258.488 us; speedup vs baseline: 1.0385x; 1.0385x over previous
//
#include <hip/hip_runtime.h>
#include <hip/hip_bf16.h>
#include <math.h>

typedef __bf16 bf16;
typedef __bf16 bf16x4 __attribute__((ext_vector_type(4)));
typedef __bf16 bf16x8 __attribute__((ext_vector_type(8)));
typedef float  f32x4  __attribute__((ext_vector_type(4)));

#define B_  4
#define S_  2048
#define D_  1024
#define H_  16
#define DH  64
#define M_  (B_*S_)      // 8192
#define BH_ (B_*H_)      // 64

// 1/sqrt(64) * log2(e): folded into Q so attn uses exp2 directly
#define QSCALE 0.18033688011112042f

__device__ __forceinline__ void glds16(const bf16* g, bf16* l) {
  __builtin_amdgcn_global_load_lds((const __attribute__((address_space(1))) void*)g,
                                   (__attribute__((address_space(3))) void*)l, 16, 0, 0);
}

// -------------------- prep: hidden fp32->bf16 + both weight transposes (R4 exact) -----------
__global__ __launch_bounds__(256) void prep(const float* __restrict__ hidden, bf16* __restrict__ hb,
                                            const float* __restrict__ wqkv, const float* __restrict__ wout,
                                            bf16* __restrict__ wqkvT, bf16* __restrict__ woutT) {
  int bx = blockIdx.x, tid = threadIdx.x;
  if (bx < 8192) {
    int i = (bx * 256 + tid) * 4;
    float4 v = *(const float4*)(hidden + i);
    bf16x4 o = { (bf16)v.x, (bf16)v.y, (bf16)v.z, (bf16)v.w };
    *(bf16x4*)(hb + i) = o;
    return;
  }
  __shared__ float tile[32][33];
  int t = bx - 8192;
  const float* in; bf16* out; int C, c0, r0;
  if (t < 96 * 32) { in = wqkv; out = wqkvT; C = 3072; c0 = (t % 96) * 32; r0 = (t / 96) * 32; }
  else { t -= 96 * 32;  in = wout; out = woutT; C = 1024; c0 = (t % 32) * 32; r0 = (t / 32) * 32; }
  int tx = tid & 31, ty = tid >> 5;
  #pragma unroll
  for (int i = ty; i < 32; i += 8) tile[i][tx] = in[(size_t)(r0 + i) * C + c0 + tx];
  __syncthreads();
  #pragma unroll
  for (int i = ty; i < 32; i += 8) out[(size_t)(c0 + i) * D_ + r0 + tx] = (bf16)tile[tx][i];
}

// ==================== 256x128 GEMM core (R4 exact: session-best 253.8us) =====================
#define BM 256
#define BN 128
#define BK 64
#define NTILE (D_ / BK)        // 16
#define ATILE (BM * BK)        // 16384 elems (32 KiB)
#define BTILE (BN * BK)        // 8192 elems  (16 KiB)

__device__ __forceinline__ void core256(const bf16* __restrict__ A, const bf16* __restrict__ Bt,
                                        int m0, int n0, bf16* As, bf16* Bs, int tid,
                                        f32x4 acc[4][4]) {
  const int wave = tid >> 6, lane = tid & 63, quad = lane >> 4, l16 = lane & 15;
  const int wm = (wave >> 1) * 64, wn = (wave & 1) * 64;
  const int lr8 = lane >> 3, lg = lane & 7;
  const int sg = ((lg ^ lr8) << 3);                 // pre-swizzled source granule (elements)
  const bf16* gA = A  + (size_t)(m0 + lr8) * D_ + sg;
  const bf16* gB = Bt + (size_t)(n0 + lr8) * D_ + sg;
  const int swq  = ((quad ^ (l16 & 7)) << 3);       // read-side swizzle, kh=0 (granule quad)
  const int swq4 = (((4 + quad) ^ (l16 & 7)) << 3); // kh=1 (granule 4+quad)

#define STAGE_H1(slot, kt) do {                                                    \
    int koff = (kt) * BK;                                                          \
    bf16* a_d = As + (slot) * ATILE + wave * 2048;                                 \
    bf16* b_d = Bs + (slot) * BTILE + wave * 1024;                                 \
    glds16(gA + (size_t)(wave * 32 + 0) * D_ + koff, a_d + 0 * 512);               \
    glds16(gA + (size_t)(wave * 32 + 8) * D_ + koff, a_d + 1 * 512);               \
    glds16(gB + (size_t)(wave * 16 + 0) * D_ + koff, b_d + 0 * 512);               \
  } while (0)

#define STAGE_H2(slot, kt) do {                                                    \
    int koff = (kt) * BK;                                                          \
    bf16* a_d = As + (slot) * ATILE + wave * 2048;                                 \
    bf16* b_d = Bs + (slot) * BTILE + wave * 1024;                                 \
    glds16(gA + (size_t)(wave * 32 + 16) * D_ + koff, a_d + 2 * 512);              \
    glds16(gA + (size_t)(wave * 32 + 24) * D_ + koff, a_d + 3 * 512);              \
    glds16(gB + (size_t)(wave * 16 + 8)  * D_ + koff, b_d + 1 * 512);              \
  } while (0)

#define RDFRAG(slot, sw, af, bfr) do {                                             \
    const bf16* a_s = As + (slot) * ATILE;                                         \
    const bf16* b_s = Bs + (slot) * BTILE;                                         \
    _Pragma("unroll")                                                              \
    for (int i_ = 0; i_ < 4; i_++) af[i_]  = *(const bf16x8*)(a_s + (wm + i_ * 16 + l16) * 64 + (sw)); \
    _Pragma("unroll")                                                              \
    for (int j_ = 0; j_ < 4; j_++) bfr[j_] = *(const bf16x8*)(b_s + (wn + j_ * 16 + l16) * 64 + (sw)); \
  } while (0)

#define MFMA16(af, bfr) do {                                                       \
    _Pragma("unroll")                                                              \
    for (int i_ = 0; i_ < 4; i_++)                                                 \
      _Pragma("unroll")                                                            \
      for (int j_ = 0; j_ < 4; j_++)                                               \
        acc[i_][j_] = __builtin_amdgcn_mfma_f32_16x16x32_bf16(af[i_], bfr[j_], acc[i_][j_], 0, 0, 0); \
  } while (0)

#define PHASE256(slot, sw, STG, VMW, ENDBAR) do {                                  \
    bf16x8 af_[4], bf_[4];                                                         \
    RDFRAG(slot, sw, af_, bf_);                                                    \
    STG;                                                                           \
    __builtin_amdgcn_sched_barrier(0);                                             \
    __builtin_amdgcn_s_barrier();                                                  \
    asm volatile("s_waitcnt lgkmcnt(0)" ::: "memory");                             \
    __builtin_amdgcn_sched_barrier(0);                                             \
    __builtin_amdgcn_s_setprio(1);                                                 \
    MFMA16(af_, bf_);                                                              \
    __builtin_amdgcn_s_setprio(0);                                                 \
    __builtin_amdgcn_sched_barrier(0);                                             \
    VMW;                                                                           \
    if (ENDBAR) { __builtin_amdgcn_s_barrier(); __builtin_amdgcn_sched_barrier(0); } \
  } while (0)

  STAGE_H1(0, 0); STAGE_H2(0, 0); STAGE_H1(1, 1); STAGE_H2(1, 1);
  asm volatile("s_waitcnt vmcnt(6)" ::: "memory");
  __builtin_amdgcn_sched_barrier(0);
  __builtin_amdgcn_s_barrier();
  __builtin_amdgcn_sched_barrier(0);

  int scur = 0, snxt = 2;
  for (int t = 0; t < NTILE - 2; t++) {            // t = 0..13: full pipeline
    PHASE256(scur, swq,  STAGE_H1(snxt, t + 2), (void)0, 1);
    PHASE256(scur, swq4, STAGE_H2(snxt, t + 2),
             asm volatile("s_waitcnt vmcnt(6)" ::: "memory"), 1);
    scur = (scur == 2) ? 0 : scur + 1;
    snxt = (snxt == 2) ? 0 : snxt + 1;
  }
  // t = 14: no prefetch; drain to 0 (tile 15 lands)
  PHASE256(scur, swq,  (void)0, (void)0, 1);
  PHASE256(scur, swq4, (void)0, asm volatile("s_waitcnt vmcnt(0)" ::: "memory"), 1);
  scur = (scur == 2) ? 0 : scur + 1;
  // t = 15: last tile, no end barrier after final phase
  PHASE256(scur, swq,  (void)0, (void)0, 1);
  PHASE256(scur, swq4, (void)0, (void)0, 0);
#undef STAGE_H1
#undef STAGE_H2
#undef RDFRAG
#undef MFMA16
#undef PHASE256
}

// GEMM1: qkv = hidden @ w_qkv (R4 exact). Q gets QSCALE folded in; V written transposed.
__global__ __launch_bounds__(512, 1) void gemm_qkv(const bf16* __restrict__ A, const bf16* __restrict__ Bt,
                                                   bf16* __restrict__ Qb, bf16* __restrict__ Kb,
                                                   bf16* __restrict__ Vtb) {
  __shared__ __attribute__((aligned(16))) bf16 As[3 * ATILE];
  __shared__ __attribute__((aligned(16))) bf16 Bs[3 * BTILE];
  int tid = threadIdx.x;
  int m0 = blockIdx.y * BM, n0 = blockIdx.x * BN;
  f32x4 acc[4][4] = {};
  core256(A, Bt, m0, n0, As, Bs, tid, acc);
  int wave = tid >> 6, lane = tid & 63, quad = lane >> 4, l16 = lane & 15;
  int wm = (wave >> 1) * 64, wn = (wave & 1) * 64;
  int which = n0 >> 10;                 // 0=Q 1=K 2=V, block-uniform
  if (which == 2) {
    #pragma unroll
    for (int i = 0; i < 4; i++) {
      int mb = m0 + wm + i * 16 + quad * 4;
      int b = mb >> 11, s = mb & 2047;
      #pragma unroll
      for (int j = 0; j < 4; j++) {
        int n = n0 + wn + j * 16 + l16;
        int h = (n >> 6) & 15, dd = n & 63;
        bf16x4 v4 = { (bf16)acc[i][j][0], (bf16)acc[i][j][1], (bf16)acc[i][j][2], (bf16)acc[i][j][3] };
        *(bf16x4*)(Vtb + ((size_t)(b * H_ + h) * DH + dd) * S_ + s) = v4;
      }
    }
  } else {
    bf16* dst = (which == 0) ? Qb : Kb;
    float sc = (which == 0) ? QSCALE : 1.0f;
    #pragma unroll
    for (int i = 0; i < 4; i++) {
      #pragma unroll
      for (int j = 0; j < 4; j++) {
        int n = n0 + wn + j * 16 + l16;
        int h = (n >> 6) & 15, dd = n & 63;
        #pragma unroll
        for (int r = 0; r < 4; r++) {
          int m = m0 + wm + i * 16 + quad * 4 + r;
          int b = m >> 11, s = m & 2047;
          dst[(((size_t)(b * H_ + h)) * S_ + s) * DH + dd] = (bf16)(acc[i][j][r] * sc);
        }
      }
    }
  }
}

// GEMM2: out = ctx @ w_out, fp32 output (R4 exact).
__global__ __launch_bounds__(512, 1) void gemm_out(const bf16* __restrict__ A, const bf16* __restrict__ Bt,
                                                   float* __restrict__ C) {
  __shared__ __attribute__((aligned(16))) bf16 As[3 * ATILE];
  __shared__ __attribute__((aligned(16))) bf16 Bs[3 * BTILE];
  int tid = threadIdx.x;
  int m0 = blockIdx.x * BM, n0 = blockIdx.y * BN;
  f32x4 acc[4][4] = {};
  core256(A, Bt, m0, n0, As, Bs, tid, acc);
  int wave = tid >> 6, lane = tid & 63, quad = lane >> 4, l16 = lane & 15;
  int wm = (wave >> 1) * 64, wn = (wave & 1) * 64;
  #pragma unroll
  for (int i = 0; i < 4; i++)
    #pragma unroll
    for (int j = 0; j < 4; j++) {
      int n = n0 + wn + j * 16 + l16;
      #pragma unroll
      for (int r = 0; r < 4; r++) {
        int m = m0 + wm + i * 16 + quad * 4 + r;
        C[(size_t)m * D_ + n] = acc[i][j][r];
      }
    }
}

// -------------------- flash attention: R7 occupancy experiment ------------------------------
// Diagnosis: grid 512 = exactly 2 blocks/CU -> 2 waves/SIMD; QK->exp2->Ps->PV dependency chain
// unhidden (MfmaUtil 39%, VALUBusy 36%, Occupancy 18%, nothing saturated = latency-bound).
// Change: per-wave q-tile 64 -> 32 rows (nq 4 -> 2), grid y 8 -> 16 => 1024 blocks = 4/CU,
// LDS 48 -> 40 KB, per-wave state halved, __launch_bounds__(256,4) => 4 waves/SIMD.
// All swizzles / index forms preserved; only the nq range and Ps row-count change.
#define NT  (S_ / 64)

#define KVSW(row, col) (((row) * 64) + ((col) ^ (((row) & 7) << 3)))
#define PSW(row, col)  (((row) * 32) + ((col) ^ ((((row) >> 1) & 3) << 3)))

__global__ __launch_bounds__(256, 4) void attn(const bf16* __restrict__ Qb, const bf16* __restrict__ Kb,
                                               const bf16* __restrict__ Vtb, bf16* __restrict__ ctx) {
  __shared__ __attribute__((aligned(16))) bf16 Ks[2][64 * 64];   // [buf][key][dd], swizzled (16KB)
  __shared__ __attribute__((aligned(16))) bf16 Vs[2][64 * 64];   // [buf][dd][key], swizzled (16KB)
  __shared__ __attribute__((aligned(16))) bf16 Ps[4][32 * 32];   // per-wave P half: [q(32)][key(32)] (8KB)
  int tid = threadIdx.x;
  int wave = tid >> 6, lane = tid & 63, quad = lane >> 4, l16 = lane & 15;
  int bh = blockIdx.x;                  // x-major: XCD = bh % 8 -> all y-blocks of a bh share one L2
  int b = bh >> 4, h = bh & 15;
  int q0 = blockIdx.y * 128 + wave * 32;
  const bf16* Qp = Qb  + (size_t)bh * S_ * DH;
  const bf16* Kp = Kb  + (size_t)bh * S_ * DH;
  const bf16* Vp = Vtb + (size_t)bh * DH * S_;

  int srow = tid >> 3, scc = (tid & 7) << 3;
  int swz = KVSW(srow, scc);            // staging slot for rows srow / srow+32 (same &7)

  bf16x8 qf[2][2];
  #pragma unroll
  for (int nq = 0; nq < 2; nq++)
    #pragma unroll
    for (int ks = 0; ks < 2; ks++)
      qf[nq][ks] = *(const bf16x8*)(Qp + (size_t)(q0 + nq * 16 + l16) * DH + ks * 32 + quad * 8);

  bf16 one1 = (bf16)1.0f;
  bf16x8 onesf = { one1, one1, one1, one1, one1, one1, one1, one1 };

  f32x4 o[2][4] = {};       // o[nq][td]: row q = quad*4+r, col dd = td*16+l16
  f32x4 oden[2] = {};       // denom(q), same row mapping

  {
    bf16x8 k0a = *(const bf16x8*)(Kp + (size_t)srow * DH + scc);
    bf16x8 k0b = *(const bf16x8*)(Kp + (size_t)(32 + srow) * DH + scc);
    bf16x8 v0a = *(const bf16x8*)(Vp + (size_t)srow * S_ + scc);
    bf16x8 v0b = *(const bf16x8*)(Vp + (size_t)(32 + srow) * S_ + scc);
    *(bf16x8*)(Ks[0] + swz)             = k0a;
    *(bf16x8*)(Ks[0] + swz + 32 * 64)   = k0b;
    *(bf16x8*)(Vs[0] + swz)             = v0a;
    *(bf16x8*)(Vs[0] + swz + 32 * 64)   = v0b;
  }

  for (int kt = 0; kt < NT; kt++) {
    int cur = kt & 1;
    __syncthreads();

    bf16x8 ka, kb2, va, vb;
    if (kt + 1 < NT) {
      const bf16* Kn = Kp + (size_t)(kt + 1) * 64 * DH;
      const bf16* Vn = Vp + (size_t)(kt + 1) * 64;
      ka  = *(const bf16x8*)(Kn + (size_t)srow * DH + scc);
      kb2 = *(const bf16x8*)(Kn + (size_t)(32 + srow) * DH + scc);
      va  = *(const bf16x8*)(Vn + (size_t)srow * S_ + scc);
      vb  = *(const bf16x8*)(Vn + (size_t)(32 + srow) * S_ + scc);
    }

    bf16x8 vf[4][2];
    #pragma unroll
    for (int td = 0; td < 4; td++)
      #pragma unroll
      for (int ks = 0; ks < 2; ks++)
        vf[td][ks] = *(const bf16x8*)(Vs[cur] + KVSW(td * 16 + l16, ks * 32 + quad * 8));

    #pragma unroll
    for (int hh = 0; hh < 2; hh++) {
      #pragma unroll
      for (int kq2 = 0; kq2 < 2; kq2++) {
        int kq = hh * 2 + kq2;
        bf16x8 kfr[2];
        #pragma unroll
        for (int ks = 0; ks < 2; ks++)
          kfr[ks] = *(const bf16x8*)(Ks[cur] + KVSW(kq * 16 + l16, ks * 32 + quad * 8));
        #pragma unroll
        for (int nq = 0; nq < 2; nq++) {
          f32x4 st = {};
          st = __builtin_amdgcn_mfma_f32_16x16x32_bf16(kfr[0], qf[nq][0], st, 0, 0, 0);
          st = __builtin_amdgcn_mfma_f32_16x16x32_bf16(kfr[1], qf[nq][1], st, 0, 0, 0);
          bf16x4 pk;
          #pragma unroll
          for (int r = 0; r < 4; r++) pk[r] = (bf16)__builtin_amdgcn_exp2f(st[r]);
          *(bf16x4*)(&Ps[wave][PSW(nq * 16 + l16, kq2 * 16 + quad * 4)]) = pk;
        }
      }
      #pragma unroll
      for (int nq = 0; nq < 2; nq++) {
        bf16x8 pf = *(const bf16x8*)(&Ps[wave][PSW(nq * 16 + l16, quad * 8)]);
        oden[nq] = __builtin_amdgcn_mfma_f32_16x16x32_bf16(pf, onesf, oden[nq], 0, 0, 0);
        #pragma unroll
        for (int td = 0; td < 4; td++)
          o[nq][td] = __builtin_amdgcn_mfma_f32_16x16x32_bf16(pf, vf[td][hh], o[nq][td], 0, 0, 0);
      }
    }

    if (kt + 1 < NT) {
      int nxt = cur ^ 1;
      *(bf16x8*)(Ks[nxt] + swz)           = ka;
      *(bf16x8*)(Ks[nxt] + swz + 32 * 64) = kb2;
      *(bf16x8*)(Vs[nxt] + swz)           = va;
      *(bf16x8*)(Vs[nxt] + swz + 32 * 64) = vb;
    }
  }

  #pragma unroll
  for (int nq = 0; nq < 2; nq++) {
    #pragma unroll
    for (int r = 0; r < 4; r++) {
      float inv = 1.0f / oden[nq][r];
      int q = q0 + nq * 16 + quad * 4 + r;
      #pragma unroll
      for (int td = 0; td < 4; td++) {
        int dd = td * 16 + l16;
        ctx[((size_t)(b * S_) + q) * D_ + h * DH + dd] = (bf16)(o[nq][td][r] * inv);
      }
    }
  }
}

// -------------------- host launch --------------------
extern "C" void kernel_launch(void* const* d_in, const int* in_sizes, int n_in,
                              void* d_out, int out_size, void* d_ws, size_t ws_size,
                              hipStream_t stream) {
  (void)in_sizes; (void)n_in; (void)out_size; (void)ws_size;
  const float* hidden = (const float*)d_in[0];
  const float* w_qkv  = (const float*)d_in[1];
  const float* w_out  = (const float*)d_in[2];
  float* out = (float*)d_out;

  char* ws = (char*)d_ws;
  size_t off = 0;
  bf16* hb    = (bf16*)(ws + off); off += (size_t)M_ * D_ * 2;      // hidden bf16 (reused as ctx)
  bf16* wqkvT = (bf16*)(ws + off); off += (size_t)3 * D_ * D_ * 2;  // [3072][1024]
  bf16* woutT = (bf16*)(ws + off); off += (size_t)D_ * D_ * 2;      // [1024][1024]
  bf16* Qb    = (bf16*)(ws + off); off += (size_t)M_ * D_ * 2;      // [BH][S][DH], pre-scaled
  bf16* Kb    = (bf16*)(ws + off); off += (size_t)M_ * D_ * 2;      // [BH][S][DH]
  bf16* Vtb   = (bf16*)(ws + off); off += (size_t)M_ * D_ * 2;      // [BH][DH][S]
  bf16* ctxb  = hb;  // alias: hb dead after gemm_qkv

  prep<<<8192 + 96 * 32 + 32 * 32, 256, 0, stream>>>(hidden, hb, w_qkv, w_out, wqkvT, woutT);
  gemm_qkv<<<dim3(3 * D_ / BN, M_ / BM), 512, 0, stream>>>(hb, wqkvT, Qb, Kb, Vtb);
  attn<<<dim3(BH_, S_ / 128), 256, 0, stream>>>(Qb, Kb, Vtb, ctxb);
  gemm_out<<<dim3(M_ / BM, D_ / BN), 512, 0, stream>>>(ctxb, woutT, out);
}

// Round 8
// 249.519 us; speedup vs baseline: 1.0758x; 1.0359x over previous
//
#include <hip/hip_runtime.h>
#include <hip/hip_bf16.h>
#include <math.h>

typedef __bf16 bf16;
typedef __bf16 bf16x4 __attribute__((ext_vector_type(4)));
typedef __bf16 bf16x8 __attribute__((ext_vector_type(8)));
typedef float  f32x4  __attribute__((ext_vector_type(4)));

#define B_  4
#define S_  2048
#define D_  1024
#define H_  16
#define DH  64
#define M_  (B_*S_)      // 8192
#define BH_ (B_*H_)      // 64

// 1/sqrt(64) * log2(e): folded into Q so attn uses exp2 directly
#define QSCALE 0.18033688011112042f

__device__ __forceinline__ void glds16(const bf16* g, bf16* l) {
  __builtin_amdgcn_global_load_lds((const __attribute__((address_space(1))) void*)g,
                                   (__attribute__((address_space(3))) void*)l, 16, 0, 0);
}

// -------------------- prep: hidden fp32->bf16 + both weight transposes (R4 exact) -----------
__global__ __launch_bounds__(256) void prep(const float* __restrict__ hidden, bf16* __restrict__ hb,
                                            const float* __restrict__ wqkv, const float* __restrict__ wout,
                                            bf16* __restrict__ wqkvT, bf16* __restrict__ woutT) {
  int bx = blockIdx.x, tid = threadIdx.x;
  if (bx < 8192) {
    int i = (bx * 256 + tid) * 4;
    float4 v = *(const float4*)(hidden + i);
    bf16x4 o = { (bf16)v.x, (bf16)v.y, (bf16)v.z, (bf16)v.w };
    *(bf16x4*)(hb + i) = o;
    return;
  }
  __shared__ float tile[32][33];
  int t = bx - 8192;
  const float* in; bf16* out; int C, c0, r0;
  if (t < 96 * 32) { in = wqkv; out = wqkvT; C = 3072; c0 = (t % 96) * 32; r0 = (t / 96) * 32; }
  else { t -= 96 * 32;  in = wout; out = woutT; C = 1024; c0 = (t % 32) * 32; r0 = (t / 32) * 32; }
  int tx = tid & 31, ty = tid >> 5;
  #pragma unroll
  for (int i = ty; i < 32; i += 8) tile[i][tx] = in[(size_t)(r0 + i) * C + c0 + tx];
  __syncthreads();
  #pragma unroll
  for (int i = ty; i < 32; i += 8) out[(size_t)(c0 + i) * D_ + r0 + tx] = (bf16)tile[tx][i];
}

// ==================== 256x128 GEMM core (benched-253.8 structure, unchanged) =================
#define BM 256
#define BN 128
#define BK 64
#define NTILE (D_ / BK)        // 16
#define ATILE (BM * BK)        // 16384 elems (32 KiB)
#define BTILE (BN * BK)        // 8192 elems  (16 KiB)

__device__ __forceinline__ void core256(const bf16* __restrict__ A, const bf16* __restrict__ Bt,
                                        int m0, int n0, bf16* As, bf16* Bs, int tid,
                                        f32x4 acc[4][4]) {
  const int wave = tid >> 6, lane = tid & 63, quad = lane >> 4, l16 = lane & 15;
  const int wm = (wave >> 1) * 64, wn = (wave & 1) * 64;
  const int lr8 = lane >> 3, lg = lane & 7;
  const int sg = ((lg ^ lr8) << 3);                 // pre-swizzled source granule (elements)
  const bf16* gA = A  + (size_t)(m0 + lr8) * D_ + sg;
  const bf16* gB = Bt + (size_t)(n0 + lr8) * D_ + sg;
  const int swq  = ((quad ^ (l16 & 7)) << 3);       // read-side swizzle, kh=0 (granule quad)
  const int swq4 = (((4 + quad) ^ (l16 & 7)) << 3); // kh=1 (granule 4+quad)

#define STAGE_H1(slot, kt) do {                                                    \
    int koff = (kt) * BK;                                                          \
    bf16* a_d = As + (slot) * ATILE + wave * 2048;                                 \
    bf16* b_d = Bs + (slot) * BTILE + wave * 1024;                                 \
    glds16(gA + (size_t)(wave * 32 + 0) * D_ + koff, a_d + 0 * 512);               \
    glds16(gA + (size_t)(wave * 32 + 8) * D_ + koff, a_d + 1 * 512);               \
    glds16(gB + (size_t)(wave * 16 + 0) * D_ + koff, b_d + 0 * 512);               \
  } while (0)

#define STAGE_H2(slot, kt) do {                                                    \
    int koff = (kt) * BK;                                                          \
    bf16* a_d = As + (slot) * ATILE + wave * 2048;                                 \
    bf16* b_d = Bs + (slot) * BTILE + wave * 1024;                                 \
    glds16(gA + (size_t)(wave * 32 + 16) * D_ + koff, a_d + 2 * 512);              \
    glds16(gA + (size_t)(wave * 32 + 24) * D_ + koff, a_d + 3 * 512);              \
    glds16(gB + (size_t)(wave * 16 + 8)  * D_ + koff, b_d + 1 * 512);              \
  } while (0)

#define RDFRAG(slot, sw, af, bfr) do {                                             \
    const bf16* a_s = As + (slot) * ATILE;                                         \
    const bf16* b_s = Bs + (slot) * BTILE;                                         \
    _Pragma("unroll")                                                              \
    for (int i_ = 0; i_ < 4; i_++) af[i_]  = *(const bf16x8*)(a_s + (wm + i_ * 16 + l16) * 64 + (sw)); \
    _Pragma("unroll")                                                              \
    for (int j_ = 0; j_ < 4; j_++) bfr[j_] = *(const bf16x8*)(b_s + (wn + j_ * 16 + l16) * 64 + (sw)); \
  } while (0)

#define MFMA16(af, bfr) do {                                                       \
    _Pragma("unroll")                                                              \
    for (int i_ = 0; i_ < 4; i_++)                                                 \
      _Pragma("unroll")                                                            \
      for (int j_ = 0; j_ < 4; j_++)                                               \
        acc[i_][j_] = __builtin_amdgcn_mfma_f32_16x16x32_bf16(af[i_], bfr[j_], acc[i_][j_], 0, 0, 0); \
  } while (0)

#define PHASE256(slot, sw, STG, VMW, ENDBAR) do {                                  \
    bf16x8 af_[4], bf_[4];                                                         \
    RDFRAG(slot, sw, af_, bf_);                                                    \
    STG;                                                                           \
    __builtin_amdgcn_sched_barrier(0);                                             \
    __builtin_amdgcn_s_barrier();                                                  \
    asm volatile("s_waitcnt lgkmcnt(0)" ::: "memory");                             \
    __builtin_amdgcn_sched_barrier(0);                                             \
    __builtin_amdgcn_s_setprio(1);                                                 \
    MFMA16(af_, bf_);                                                              \
    __builtin_amdgcn_s_setprio(0);                                                 \
    __builtin_amdgcn_sched_barrier(0);                                             \
    VMW;                                                                           \
    if (ENDBAR) { __builtin_amdgcn_s_barrier(); __builtin_amdgcn_sched_barrier(0); } \
  } while (0)

  STAGE_H1(0, 0); STAGE_H2(0, 0); STAGE_H1(1, 1); STAGE_H2(1, 1);
  asm volatile("s_waitcnt vmcnt(6)" ::: "memory");
  __builtin_amdgcn_sched_barrier(0);
  __builtin_amdgcn_s_barrier();
  __builtin_amdgcn_sched_barrier(0);

  int scur = 0, snxt = 2;
  for (int t = 0; t < NTILE - 2; t++) {            // t = 0..13: full pipeline
    PHASE256(scur, swq,  STAGE_H1(snxt, t + 2), (void)0, 1);
    PHASE256(scur, swq4, STAGE_H2(snxt, t + 2),
             asm volatile("s_waitcnt vmcnt(6)" ::: "memory"), 1);
    scur = (scur == 2) ? 0 : scur + 1;
    snxt = (snxt == 2) ? 0 : snxt + 1;
  }
  // t = 14: no prefetch; drain to 0 (tile 15 lands)
  PHASE256(scur, swq,  (void)0, (void)0, 1);
  PHASE256(scur, swq4, (void)0, asm volatile("s_waitcnt vmcnt(0)" ::: "memory"), 1);
  scur = (scur == 2) ? 0 : scur + 1;
  // t = 15: last tile, no end barrier after final phase
  PHASE256(scur, swq,  (void)0, (void)0, 1);
  PHASE256(scur, swq4, (void)0, (void)0, 0);
#undef STAGE_H1
#undef STAGE_H2
#undef RDFRAG
#undef MFMA16
#undef PHASE256
}

// GEMM1: qkv = hidden @ w_qkv. Q gets QSCALE folded in; V written transposed.
__global__ __launch_bounds__(512, 1) void gemm_qkv(const bf16* __restrict__ A, const bf16* __restrict__ Bt,
                                                   bf16* __restrict__ Qb, bf16* __restrict__ Kb,
                                                   bf16* __restrict__ Vtb) {
  __shared__ __attribute__((aligned(16))) bf16 As[3 * ATILE];
  __shared__ __attribute__((aligned(16))) bf16 Bs[3 * BTILE];
  int tid = threadIdx.x;
  int m0 = blockIdx.y * BM, n0 = blockIdx.x * BN;
  f32x4 acc[4][4] = {};
  core256(A, Bt, m0, n0, As, Bs, tid, acc);
  int wave = tid >> 6, lane = tid & 63, quad = lane >> 4, l16 = lane & 15;
  int wm = (wave >> 1) * 64, wn = (wave & 1) * 64;
  int which = n0 >> 10;                 // 0=Q 1=K 2=V, block-uniform
  if (which == 2) {
    #pragma unroll
    for (int i = 0; i < 4; i++) {
      int mb = m0 + wm + i * 16 + quad * 4;
      int b = mb >> 11, s = mb & 2047;
      #pragma unroll
      for (int j = 0; j < 4; j++) {
        int n = n0 + wn + j * 16 + l16;
        int h = (n >> 6) & 15, dd = n & 63;
        bf16x4 v4 = { (bf16)acc[i][j][0], (bf16)acc[i][j][1], (bf16)acc[i][j][2], (bf16)acc[i][j][3] };
        *(bf16x4*)(Vtb + ((size_t)(b * H_ + h) * DH + dd) * S_ + s) = v4;
      }
    }
  } else {
    bf16* dst = (which == 0) ? Qb : Kb;
    float sc = (which == 0) ? QSCALE : 1.0f;
    #pragma unroll
    for (int i = 0; i < 4; i++) {
      #pragma unroll
      for (int j = 0; j < 4; j++) {
        int n = n0 + wn + j * 16 + l16;
        int h = (n >> 6) & 15, dd = n & 63;
        #pragma unroll
        for (int r = 0; r < 4; r++) {
          int m = m0 + wm + i * 16 + quad * 4 + r;
          int b = m >> 11, s = m & 2047;
          dst[(((size_t)(b * H_ + h)) * S_ + s) * DH + dd] = (bf16)(acc[i][j][r] * sc);
        }
      }
    }
  }
}

// GEMM2: out = ctx @ w_out, fp32 output.
__global__ __launch_bounds__(512, 1) void gemm_out(const bf16* __restrict__ A, const bf16* __restrict__ Bt,
                                                   float* __restrict__ C) {
  __shared__ __attribute__((aligned(16))) bf16 As[3 * ATILE];
  __shared__ __attribute__((aligned(16))) bf16 Bs[3 * BTILE];
  int tid = threadIdx.x;
  int m0 = blockIdx.x * BM, n0 = blockIdx.y * BN;
  f32x4 acc[4][4] = {};
  core256(A, Bt, m0, n0, As, Bs, tid, acc);
  int wave = tid >> 6, lane = tid & 63, quad = lane >> 4, l16 = lane & 15;
  int wm = (wave >> 1) * 64, wn = (wave & 1) * 64;
  #pragma unroll
  for (int i = 0; i < 4; i++)
    #pragma unroll
    for (int j = 0; j < 4; j++) {
      int n = n0 + wn + j * 16 + l16;
      #pragma unroll
      for (int r = 0; r < 4; r++) {
        int m = m0 + wm + i * 16 + quad * 4 + r;
        C[(size_t)m * D_ + n] = acc[i][j][r];
      }
    }
}

// -------------------- flash attention: R8 = best 64q config + glds16 K/V staging ------------
// R7 refuted occupancy theory (31% occ, same dur, MfmaUtil pinned 39%) -> issue-count-bound.
// Change vs the 81.3us R2 config: K/V staging via global_load_lds with PRE-SWIZZLED global
// source (m173): LDS dest lane-linear (m104 requirement), source granule g^(row&7). The
// existing KVSW read addressing is the same involution -> byte-identical LDS contents.
// Deletes 4 ds_write_b128 + 4 global_load_dwordx4->reg per tile per wave (-16 VGPR).
// Overlap preserved: glds for buf nxt issued at tile top; drained by NEXT tile-top
// __syncthreads (compiler vmcnt(0) before barrier); buf nxt dead at issue (read 2 tiles ago).
#define NT  (S_ / 64)

#define KVSW(row, col) (((row) * 64) + ((col) ^ (((row) & 7) << 3)))
#define PSW(row, col)  (((row) * 32) + ((col) ^ ((((row) >> 1) & 3) << 3)))

__global__ __launch_bounds__(256, 2) void attn(const bf16* __restrict__ Qb, const bf16* __restrict__ Kb,
                                               const bf16* __restrict__ Vtb, bf16* __restrict__ ctx) {
  __shared__ __attribute__((aligned(16))) bf16 Ks[2][64 * 64];   // [buf][key][dd], swizzled
  __shared__ __attribute__((aligned(16))) bf16 Vs[2][64 * 64];   // [buf][dd][key], swizzled
  __shared__ __attribute__((aligned(16))) bf16 Ps[4][64 * 32];   // per-wave P half: [q(64)][key(32)]
  int tid = threadIdx.x;
  int wave = tid >> 6, lane = tid & 63, quad = lane >> 4, l16 = lane & 15;
  int bh = blockIdx.x;                  // x-major: XCD = bh % 8 -> K/V working set stays in one L2
  int b = bh >> 4, h = bh & 15;
  int q0 = blockIdx.y * 256 + wave * 64;
  const bf16* Qp = Qb  + (size_t)bh * S_ * DH;
  const bf16* Kp = Kb  + (size_t)bh * S_ * DH;
  const bf16* Vp = Vtb + (size_t)bh * DH * S_;

  // glds staging: thread -> row sr (0..31 within half), granule g; source pre-swizzled gs.
  int sr = tid >> 3, g = tid & 7;
  int gs8 = (g ^ (sr & 7)) << 3;        // swizzled source granule offset (elements)
  int dst = sr * 64 + g * 8;            // lane-linear LDS slot (= wave base + lane*16B)

  bf16x8 qf[4][2];
  #pragma unroll
  for (int nq = 0; nq < 4; nq++)
    #pragma unroll
    for (int ks = 0; ks < 2; ks++)
      qf[nq][ks] = *(const bf16x8*)(Qp + (size_t)(q0 + nq * 16 + l16) * DH + ks * 32 + quad * 8);

  bf16 one1 = (bf16)1.0f;
  bf16x8 onesf = { one1, one1, one1, one1, one1, one1, one1, one1 };

  f32x4 o[4][4] = {};       // o[nq][td]: row q = quad*4+r, col dd = td*16+l16
  f32x4 oden[4] = {};       // denom(q), same row mapping

  // prologue: stage tile 0 directly to LDS (drained by first loop-top __syncthreads)
  glds16(Kp + (size_t)sr * DH + gs8,        Ks[0] + dst);
  glds16(Kp + (size_t)(32 + sr) * DH + gs8, Ks[0] + 32 * 64 + dst);
  glds16(Vp + (size_t)sr * S_ + gs8,        Vs[0] + dst);
  glds16(Vp + (size_t)(32 + sr) * S_ + gs8, Vs[0] + 32 * 64 + dst);

  for (int kt = 0; kt < NT; kt++) {
    int cur = kt & 1;
    __syncthreads();                    // vmcnt(0)+barrier: tile cur landed for all waves

    if (kt + 1 < NT) {                  // prefetch next tile into dead buffer (wave-uniform branch)
      int nxt = cur ^ 1;
      const bf16* Kn = Kp + (size_t)(kt + 1) * 64 * DH;
      const bf16* Vn = Vp + (size_t)(kt + 1) * 64;
      glds16(Kn + (size_t)sr * DH + gs8,        Ks[nxt] + dst);
      glds16(Kn + (size_t)(32 + sr) * DH + gs8, Ks[nxt] + 32 * 64 + dst);
      glds16(Vn + (size_t)sr * S_ + gs8,        Vs[nxt] + dst);
      glds16(Vn + (size_t)(32 + sr) * S_ + gs8, Vs[nxt] + 32 * 64 + dst);
    }

    bf16x8 vf[4][2];
    #pragma unroll
    for (int td = 0; td < 4; td++)
      #pragma unroll
      for (int ks = 0; ks < 2; ks++)
        vf[td][ks] = *(const bf16x8*)(Vs[cur] + KVSW(td * 16 + l16, ks * 32 + quad * 8));

    #pragma unroll
    for (int hh = 0; hh < 2; hh++) {
      #pragma unroll
      for (int kq2 = 0; kq2 < 2; kq2++) {
        int kq = hh * 2 + kq2;
        bf16x8 kfr[2];
        #pragma unroll
        for (int ks = 0; ks < 2; ks++)
          kfr[ks] = *(const bf16x8*)(Ks[cur] + KVSW(kq * 16 + l16, ks * 32 + quad * 8));
        #pragma unroll
        for (int nq = 0; nq < 4; nq++) {
          f32x4 st = {};
          st = __builtin_amdgcn_mfma_f32_16x16x32_bf16(kfr[0], qf[nq][0], st, 0, 0, 0);
          st = __builtin_amdgcn_mfma_f32_16x16x32_bf16(kfr[1], qf[nq][1], st, 0, 0, 0);
          bf16x4 pk;
          #pragma unroll
          for (int r = 0; r < 4; r++) pk[r] = (bf16)__builtin_amdgcn_exp2f(st[r]);
          *(bf16x4*)(&Ps[wave][PSW(nq * 16 + l16, kq2 * 16 + quad * 4)]) = pk;
        }
      }
      #pragma unroll
      for (int nq = 0; nq < 4; nq++) {
        bf16x8 pf = *(const bf16x8*)(&Ps[wave][PSW(nq * 16 + l16, quad * 8)]);
        oden[nq] = __builtin_amdgcn_mfma_f32_16x16x32_bf16(pf, onesf, oden[nq], 0, 0, 0);
        #pragma unroll
        for (int td = 0; td < 4; td++)
          o[nq][td] = __builtin_amdgcn_mfma_f32_16x16x32_bf16(pf, vf[td][hh], o[nq][td], 0, 0, 0);
      }
    }
  }

  #pragma unroll
  for (int nq = 0; nq < 4; nq++) {
    #pragma unroll
    for (int r = 0; r < 4; r++) {
      float inv = 1.0f / oden[nq][r];
      int q = q0 + nq * 16 + quad * 4 + r;
      #pragma unroll
      for (int td = 0; td < 4; td++) {
        int dd = td * 16 + l16;
        ctx[((size_t)(b * S_) + q) * D_ + h * DH + dd] = (bf16)(o[nq][td][r] * inv);
      }
    }
  }
}

// -------------------- host launch --------------------
extern "C" void kernel_launch(void* const* d_in, const int* in_sizes, int n_in,
                              void* d_out, int out_size, void* d_ws, size_t ws_size,
                              hipStream_t stream) {
  (void)in_sizes; (void)n_in; (void)out_size; (void)ws_size;
  const float* hidden = (const float*)d_in[0];
  const float* w_qkv  = (const float*)d_in[1];
  const float* w_out  = (const float*)d_in[2];
  float* out = (float*)d_out;

  char* ws = (char*)d_ws;
  size_t off = 0;
  bf16* hb    = (bf16*)(ws + off); off += (size_t)M_ * D_ * 2;      // hidden bf16 (reused as ctx)
  bf16* wqkvT = (bf16*)(ws + off); off += (size_t)3 * D_ * D_ * 2;  // [3072][1024]
  bf16* woutT = (bf16*)(ws + off); off += (size_t)D_ * D_ * 2;      // [1024][1024]
  bf16* Qb    = (bf16*)(ws + off); off += (size_t)M_ * D_ * 2;      // [BH][S][DH], pre-scaled
  bf16* Kb    = (bf16*)(ws + off); off += (size_t)M_ * D_ * 2;      // [BH][S][DH]
  bf16* Vtb   = (bf16*)(ws + off); off += (size_t)M_ * D_ * 2;      // [BH][DH][S]
  bf16* ctxb  = hb;  // alias: hb dead after gemm_qkv

  prep<<<8192 + 96 * 32 + 32 * 32, 256, 0, stream>>>(hidden, hb, w_qkv, w_out, wqkvT, woutT);
  gemm_qkv<<<dim3(3 * D_ / BN, M_ / BM), 512, 0, stream>>>(hb, wqkvT, Qb, Kb, Vtb);
  attn<<<dim3(BH_, S_ / 256), 256, 0, stream>>>(Qb, Kb, Vtb, ctxb);
  gemm_out<<<dim3(M_ / BM, D_ / BN), 512, 0, stream>>>(ctxb, woutT, out);
}